// Round 7
// baseline (94.675 us; speedup 1.0000x reference)
//
#include <hip/hip_runtime.h>
#include <math.h>

// NG=4, N=6, NFG=8, NFR=256, NACT=5, B=32768
// sim factorization: sim[g,n,m] = (f_n^T M_g f_m + U_g.f_n + V_g.f_m + C_g)/16
// ws layout (floats), R2/R6-proven, UNSCALED:
//   M[g*64+f1*8+f2] @0, U[g*8+f] @256, V[g*8+f] @288, C[g] @320   (324 floats)

// ===== R6's precompute, VERBATIM (proven) =====
__launch_bounds__(256)
__global__ void gcn_precompute(const float* __restrict__ Wt, const float* __restrict__ bt,
                               const float* __restrict__ Wp, const float* __restrict__ bp,
                               float* __restrict__ ws) {
  const int wave = threadIdx.x >> 6, lane = threadIdx.x & 63;
  const int tau = blockIdx.x * 4 + wave;  // 81*4 = 324 exactly
  const float *cA, *cB;
  int sA, sB;
  if (tau < 256) {            // M[g][f1][f2] = sum_r Wt[g,r,f1]*Wp[g,r,f2]
    const int g = tau >> 6, f1 = (tau >> 3) & 7, f2 = tau & 7;
    cA = Wt + g * 2048 + f1; sA = 8;
    cB = Wp + g * 2048 + f2; sB = 8;
  } else if (tau < 288) {     // U[g][f] = sum_r Wt[g,r,f]*bp[g,r]
    const int i = tau - 256, g = i >> 3, f = i & 7;
    cA = Wt + g * 2048 + f;  sA = 8;
    cB = bp + g * 256;       sB = 1;
  } else if (tau < 320) {     // V[g][f] = sum_r Wp[g,r,f]*bt[g,r]
    const int i = tau - 288, g = i >> 3, f = i & 7;
    cA = Wp + g * 2048 + f;  sA = 8;
    cB = bt + g * 256;       sB = 1;
  } else {                    // C[g] = sum_r bt[g,r]*bp[g,r]
    const int g = tau - 320;
    cA = bt + g * 256; sA = 1;
    cB = bp + g * 256; sB = 1;
  }
  float s = 0.0f;
#pragma unroll
  for (int i = 0; i < 4; ++i) {
    const int r = lane + 64 * i;
    s = fmaf(cA[r * sA], cB[r * sB], s);
  }
#pragma unroll
  for (int off = 1; off < 64; off <<= 1) s += __shfl_xor(s, off, 64);
  if (lane == 0) ws[tau] = s;
}

// block=256: 32 elements/block, 8 lanes/element. sub = tid&7; g = sub&3 (group),
// h = sub>>2 (row half: lane owns softmax rows n = 3h..3h+2). grid = B/32.
// launch_bounds(256,4): force VGPR<=128 -> 4 waves/SIMD.
__launch_bounds__(256, 4)
__global__ void gcn_main(const float* __restrict__ bfeat, const float* __restrict__ pos,
                         const float* __restrict__ W_ext, const float* __restrict__ b_ext,
                         const float* __restrict__ W_gcn, const float* __restrict__ W_act,
                         const float* __restrict__ b_act, const float* __restrict__ ws,
                         float* __restrict__ out, int B) {
  __shared__ float sWext[64];
  __shared__ float sbext[8];
  __shared__ float sM[4 * 65];
  __shared__ float sU[4 * 9];
  __shared__ float sV[4 * 9];
  __shared__ float sC[4];
  __shared__ float sWgcn[4 * 65];  // pre-scaled by 0.25 (mean over NG folded in)
  __shared__ float sWact[64];      // rows 5..7 zero
  __shared__ float sbact[8];

  const int tid = threadIdx.x;
  if (tid < 64) sWext[tid] = W_ext[tid];
  if (tid < 8) sbext[tid] = b_ext[tid];
  sM[(tid >> 6) * 65 + (tid & 63)] = ws[tid];
  if (tid < 32) sU[(tid >> 3) * 9 + (tid & 7)] = ws[256 + tid];
  if (tid < 32) sV[(tid >> 3) * 9 + (tid & 7)] = ws[288 + tid];
  if (tid < 4) sC[tid] = ws[320 + tid];
  sWgcn[(tid >> 6) * 65 + (tid & 63)] = 0.25f * W_gcn[tid];
  if (tid < 64) sWact[tid] = (tid < 40) ? W_act[tid] : 0.0f;
  if (tid < 8) sbact[tid] = (tid < 5) ? b_act[tid] : 0.0f;
  __syncthreads();

  const int e = blockIdx.x * 32 + (tid >> 3);
  const int sub = tid & 7;
  const int g = sub & 3, h = sub >> 2;
  if (e >= B) return;

  // ---- loads ----
  float px[6], py[6];
  {
    const float4* p4 = (const float4*)(pos + (size_t)e * 12);
    float4 p0 = p4[0], p1 = p4[1], p2 = p4[2];
    px[0] = p0.x; py[0] = p0.y; px[1] = p0.z; py[1] = p0.w;
    px[2] = p1.x; py[2] = p1.y; px[3] = p1.z; py[3] = p1.w;
    px[4] = p2.x; py[4] = p2.y; px[5] = p2.z; py[5] = p2.w;
  }
  float bfr[6][8];
  {
    const float4* f4 = (const float4*)(bfeat + (size_t)e * 48);
#pragma unroll
    for (int i = 0; i < 12; ++i) {
      float4 v = f4[i];
      const int n = i >> 1, base = (i & 1) * 4;
      bfr[n][base + 0] = v.x; bfr[n][base + 1] = v.y;
      bfr[n][base + 2] = v.z; bfr[n][base + 3] = v.w;
    }
  }

  // ---- position mask: FULL 36 pairs, R6 VERBATIM (exact numpy fp32 sequence) ----
  float rr[6];
#pragma unroll
  for (int n = 0; n < 6; ++n)
    rr[n] = __fadd_rn(__fmul_rn(px[n], px[n]), __fmul_rn(py[n], py[n]));
  unsigned long long mask = 0ull;  // bit n*6+m set => masked (-inf)
#pragma unroll
  for (int n = 0; n < 6; ++n) {
#pragma unroll
    for (int m = 0; m < 6; ++m) {
      float dot = __fadd_rn(__fmul_rn(px[n], px[m]), __fmul_rn(py[n], py[m]));
      float d2 = __fadd_rn(__fsub_rn(rr[n], __fmul_rn(2.0f, dot)), rr[m]);
      float dist = sqrtf(d2);  // exact 0 on diag -> false (matches np)
      if (dist > 4.0f) mask |= (1ull << (n * 6 + m));
    }
  }

  // ---- feature extension: lane computes output feature o = sub for all 6 n ----
  float wx[8];
#pragma unroll
  for (int f = 0; f < 8; ++f) wx[f] = sWext[sub * 8 + f];
  const float bo = sbext[sub];
  float myo[6];
#pragma unroll
  for (int n = 0; n < 6; ++n) {
    float s = bo;
#pragma unroll
    for (int f = 0; f < 8; ++f) s = fmaf(bfr[n][f], wx[f], s);
    myo[n] = fmaxf(s, 0.0f);
  }
  // bfr dead here (residual reloaded at the end, L1-hot — R3-proven pattern)

  // ---- all-gather feat[6][8]: lanes qb..qb+7 are this element's 8 lanes ----
  const int qb = (tid & 63) & ~7;
  float feat[6][8];
#pragma unroll
  for (int n = 0; n < 6; ++n)
#pragma unroll
    for (int o = 0; o < 8; ++o) feat[n][o] = __shfl(myo[n], qb + o, 64);

  // ---- this lane's group tables ----
  const float* M = sM + g * 65;
  const float* U = sU + g * 9;
  const float* V = sV + g * 9;
  const float* Wg = sWgcn + g * 65;
  const float Cg = sC[g];

  // ---- uvall/vv for all 6 (then select my 3 uv) ----
  float uvall[6], vv[6];
#pragma unroll
  for (int m = 0; m < 6; ++m) {
    float su = 0.0f, sv = 0.0f;
#pragma unroll
    for (int f = 0; f < 8; ++f) {
      su = fmaf(U[f], feat[m][f], su);
      sv = fmaf(V[f], feat[m][f], sv);
    }
    uvall[m] = su; vv[m] = sv;
  }

  // ---- th[k][j] = sum_f1 feat[row][f1] * M[f1][j]  (row = 3h+k; row-form of R2's z) ----
  float th[3][8];
#pragma unroll
  for (int k = 0; k < 3; ++k)
#pragma unroll
    for (int j = 0; j < 8; ++j) th[k][j] = 0.0f;
#pragma unroll
  for (int f1 = 0; f1 < 8; ++f1) {
    float fv[3];
#pragma unroll
    for (int k = 0; k < 3; ++k) fv[k] = (h == 0) ? feat[k][f1] : feat[k + 3][f1];
#pragma unroll
    for (int j = 0; j < 8; ++j) {
      const float Mv = M[f1 * 8 + j];
#pragma unroll
      for (int k = 0; k < 3; ++k) th[k][j] = fmaf(fv[k], Mv, th[k][j]);
    }
  }

  // ---- sim rows + softmax -> P[3][6] (mirrors R2's rounding shape) ----
  float P[3][6];
#pragma unroll
  for (int k = 0; k < 3; ++k) {
    const float uvk = (h == 0) ? uvall[k] : uvall[k + 3];
    float simr[6];
    float rmax = -INFINITY;
#pragma unroll
    for (int m = 0; m < 6; ++m) {
      float s = 0.0f;
#pragma unroll
      for (int j = 0; j < 8; ++j) s = fmaf(th[k][j], feat[m][j], s);
      s = (s + uvk + vv[m] + Cg) * 0.0625f;
      const int bit = (3 * h + k) * 6 + m;
      const bool msk = (mask >> bit) & 1ull;
      simr[m] = msk ? -INFINITY : s;
      rmax = fmaxf(rmax, simr[m]);
    }
    float e6[6], esum = 0.0f;
#pragma unroll
    for (int m = 0; m < 6; ++m) {
      float ev = __expf(simr[m] - rmax);
      e6[m] = ev; esum += ev;
    }
    const float inv = 1.0f / esum;  // diag always unmasked
#pragma unroll
    for (int m = 0; m < 6; ++m) P[k][m] = e6[m] * inv;
  }

  // ---- agg[k] = P[k] @ feat (th dead, feat dies after) ----
  float agg[3][8];
#pragma unroll
  for (int k = 0; k < 3; ++k)
#pragma unroll
    for (int f = 0; f < 8; ++f) agg[k][f] = 0.0f;
#pragma unroll
  for (int m = 0; m < 6; ++m)
#pragma unroll
    for (int f = 0; f < 8; ++f) {
      const float fv = feat[m][f];
#pragma unroll
      for (int k = 0; k < 3; ++k) agg[k][f] = fmaf(P[k][m], fv, agg[k][f]);
    }

  // ---- con[k] = relu(0.25*Wgcn_g @ agg[k]) ----
  float con[3][8];
#pragma unroll
  for (int o = 0; o < 8; ++o) {
    float t3[3] = {0.0f, 0.0f, 0.0f};
#pragma unroll
    for (int f = 0; f < 8; ++f) {
      const float Wv = Wg[o * 8 + f];
#pragma unroll
      for (int k = 0; k < 3; ++k) t3[k] = fmaf(Wv, agg[k][f], t3[k]);
    }
#pragma unroll
    for (int k = 0; k < 3; ++k) con[k][o] = fmaxf(t3[k], 0.0f);
  }

  // ---- sum over 4 g-lanes (xor 1,2): con[k] = sum_g 0.25*relu_g for my rows ----
#pragma unroll
  for (int k = 0; k < 3; ++k)
#pragma unroll
    for (int f = 0; f < 8; ++f) {
      float v = con[k][f];
      v += __shfl_xor(v, 1);
      v += __shfl_xor(v, 2);
      con[k][f] = v;
    }

  // ---- residual: reload my 3 bfeat rows (L1-hot), states = con + bfr_row ----
  {
    const float4* f4 = (const float4*)(bfeat + (size_t)e * 48);
#pragma unroll
    for (int k = 0; k < 3; ++k) {
      const int j = (3 * h + k) * 2;
      float4 v0 = f4[j], v1 = f4[j + 1];
      con[k][0] += v0.x; con[k][1] += v0.y; con[k][2] += v0.z; con[k][3] += v0.w;
      con[k][4] += v1.x; con[k][5] += v1.y; con[k][6] += v1.z; con[k][7] += v1.w;
    }
  }

  // ---- pool: max over my 3 rows, then max across halves (xor 4) ----
  float pool8[8];
#pragma unroll
  for (int f = 0; f < 8; ++f) {
    float p = fmaxf(con[0][f], fmaxf(con[1][f], con[2][f]));
    pool8[f] = fmaxf(p, __shfl_xor(p, 4));
  }

  // ---- activity head: lane sub computes score row sub (rows 5..7 are zeros) ----
  float sc = sbact[sub];
#pragma unroll
  for (int f = 0; f < 8; ++f) sc = fmaf(pool8[f], sWact[sub * 8 + f], sc);
  if (sub < 5) out[(size_t)e * 5 + sub] = sc;
}

extern "C" void kernel_launch(void* const* d_in, const int* in_sizes, int n_in,
                              void* d_out, int out_size, void* d_ws, size_t ws_size,
                              hipStream_t stream) {
  const float* bfeat   = (const float*)d_in[0];
  const float* pos     = (const float*)d_in[1];
  const float* W_ext   = (const float*)d_in[2];
  const float* b_ext   = (const float*)d_in[3];
  const float* W_theta = (const float*)d_in[4];
  const float* b_theta = (const float*)d_in[5];
  const float* W_phi   = (const float*)d_in[6];
  const float* b_phi   = (const float*)d_in[7];
  const float* W_gcn   = (const float*)d_in[8];
  const float* W_act   = (const float*)d_in[9];
  const float* b_act   = (const float*)d_in[10];
  float* out = (float*)d_out;
  float* ws  = (float*)d_ws;

  const int B = in_sizes[0] / 48;  // [B,6,8]

  hipLaunchKernelGGL(gcn_precompute, dim3(81), dim3(256), 0, stream,
                     W_theta, b_theta, W_phi, b_phi, ws);
  const int grid = (B + 31) / 32;
  hipLaunchKernelGGL(gcn_main, dim3(grid), dim3(256), 0, stream,
                     bfeat, pos, W_ext, b_ext, W_gcn, W_act, b_act, ws, out, B);
}

// Round 8
// 89.535 us; speedup vs baseline: 1.0574x; 1.0574x over previous
//
#include <hip/hip_runtime.h>
#include <math.h>

// NG=4, N=6, NFG=8, NFR=256, NACT=5, B=32768
// sim factorization: sim[g,n,m] = (f_n^T M_g f_m + U_g.f_n + V_g.f_m + C_g)/16
// ws layout (floats), R2/R6-proven, UNSCALED:
//   M[g*64+f1*8+f2] @0, U[g*8+f] @256, V[g*8+f] @288, C[g] @320   (324 floats)

// ===== R6's precompute, VERBATIM (proven) =====
__launch_bounds__(256)
__global__ void gcn_precompute(const float* __restrict__ Wt, const float* __restrict__ bt,
                               const float* __restrict__ Wp, const float* __restrict__ bp,
                               float* __restrict__ ws) {
  const int wave = threadIdx.x >> 6, lane = threadIdx.x & 63;
  const int tau = blockIdx.x * 4 + wave;  // 81*4 = 324 exactly
  const float *cA, *cB;
  int sA, sB;
  if (tau < 256) {            // M[g][f1][f2] = sum_r Wt[g,r,f1]*Wp[g,r,f2]
    const int g = tau >> 6, f1 = (tau >> 3) & 7, f2 = tau & 7;
    cA = Wt + g * 2048 + f1; sA = 8;
    cB = Wp + g * 2048 + f2; sB = 8;
  } else if (tau < 288) {     // U[g][f] = sum_r Wt[g,r,f]*bp[g,r]
    const int i = tau - 256, g = i >> 3, f = i & 7;
    cA = Wt + g * 2048 + f;  sA = 8;
    cB = bp + g * 256;       sB = 1;
  } else if (tau < 320) {     // V[g][f] = sum_r Wp[g,r,f]*bt[g,r]
    const int i = tau - 288, g = i >> 3, f = i & 7;
    cA = Wp + g * 2048 + f;  sA = 8;
    cB = bt + g * 256;       sB = 1;
  } else {                    // C[g] = sum_r bt[g,r]*bp[g,r]
    const int g = tau - 320;
    cA = bt + g * 256; sA = 1;
    cB = bp + g * 256; sB = 1;
  }
  float s = 0.0f;
#pragma unroll
  for (int i = 0; i < 4; ++i) {
    const int r = lane + 64 * i;
    s = fmaf(cA[r * sA], cB[r * sB], s);
  }
#pragma unroll
  for (int off = 1; off < 64; off <<= 1) s += __shfl_xor(s, off, 64);
  if (lane == 0) ws[tau] = s;
}

// ===== R6's gcn_main, with ONE change: mask split 4-ways across the quad =====
// block=256: 64 elements/block, 4 lanes (one per g) per element. grid = B/64.
__launch_bounds__(256, 2)
__global__ void gcn_main(const float* __restrict__ bfeat, const float* __restrict__ pos,
                         const float* __restrict__ W_ext, const float* __restrict__ b_ext,
                         const float* __restrict__ W_gcn, const float* __restrict__ W_act,
                         const float* __restrict__ b_act, const float* __restrict__ ws,
                         float* __restrict__ out, int B) {
  __shared__ float sWext[64];
  __shared__ float sbext[8];
  __shared__ float sM[4 * 65];
  __shared__ float sU[4 * 9];
  __shared__ float sV[4 * 9];
  __shared__ float sC[4];
  __shared__ float sWgcn[4 * 65];  // pre-scaled by 0.25 (mean over NG folded in)
  __shared__ float sWact[40];
  __shared__ float sbact[5];

  const int tid = threadIdx.x;
  if (tid < 64) sWext[tid] = W_ext[tid];
  if (tid < 8) sbext[tid] = b_ext[tid];
  sM[(tid >> 6) * 65 + (tid & 63)] = ws[tid];
  if (tid < 32) sU[(tid >> 3) * 9 + (tid & 7)] = ws[256 + tid];
  if (tid < 32) sV[(tid >> 3) * 9 + (tid & 7)] = ws[288 + tid];
  if (tid < 4) sC[tid] = ws[320 + tid];
  sWgcn[(tid >> 6) * 65 + (tid & 63)] = 0.25f * W_gcn[tid];
  if (tid < 40) sWact[tid] = W_act[tid];
  if (tid < 5) sbact[tid] = b_act[tid];
  __syncthreads();

  const int e = blockIdx.x * 64 + (tid >> 2);  // batch element
  const int g = tid & 3;                       // relation group
  if (e >= B) return;

  // ---- load positions [6][2] ----
  float px[6], py[6];
  {
    const float4* p4 = (const float4*)(pos + (size_t)e * 12);
    float4 p0 = p4[0], p1 = p4[1], p2 = p4[2];
    px[0] = p0.x; py[0] = p0.y; px[1] = p0.z; py[1] = p0.w;
    px[2] = p1.x; py[2] = p1.y; px[3] = p1.z; py[3] = p1.w;
    px[4] = p2.x; py[4] = p2.y; px[5] = p2.z; py[5] = p2.w;
  }

  // ---- load raw features [6][8] ----
  float bfr[6][8];
  {
    const float4* f4 = (const float4*)(bfeat + (size_t)e * 48);
#pragma unroll
    for (int i = 0; i < 12; ++i) {
      float4 v = f4[i];
      const int n = i >> 1, base = (i & 1) * 4;
      bfr[n][base + 0] = v.x; bfr[n][base + 1] = v.y;
      bfr[n][base + 2] = v.z; bfr[n][base + 3] = v.w;
    }
  }

  // ---- position mask, 4-way split across the quad ----
  // lane (h2,q2) = (g>>1, g&1) computes rows 3*h2..3*h2+2 x cols 3*q2..3*q2+2
  // (9 pairs, EXACT per-pair numpy fp32 sequence with cndmask-selected inputs),
  // then u64 OR-combine across the quad. Bit n*6+m set => masked (-inf).
  float rr[6];
#pragma unroll
  for (int n = 0; n < 6; ++n)
    rr[n] = __fadd_rn(__fmul_rn(px[n], px[n]), __fmul_rn(py[n], py[n]));
  unsigned long long mask;
  {
    const int h2 = (g >> 1) & 1, q2 = g & 1;
    float pxn[3], pyn[3], rrn[3], pxm[3], pym[3], rrm[3];
#pragma unroll
    for (int k = 0; k < 3; ++k) {
      pxn[k] = h2 ? px[k + 3] : px[k];
      pyn[k] = h2 ? py[k + 3] : py[k];
      rrn[k] = h2 ? rr[k + 3] : rr[k];
      pxm[k] = q2 ? px[k + 3] : px[k];
      pym[k] = q2 ? py[k + 3] : py[k];
      rrm[k] = q2 ? rr[k + 3] : rr[k];
    }
    unsigned long long part = 0ull;
    const int rbase = 3 * h2, mbase = 3 * q2;
#pragma unroll
    for (int k = 0; k < 3; ++k) {
#pragma unroll
      for (int j = 0; j < 3; ++j) {
        float dot = __fadd_rn(__fmul_rn(pxn[k], pxm[j]), __fmul_rn(pyn[k], pym[j]));
        float d2 = __fadd_rn(__fsub_rn(rrn[k], __fmul_rn(2.0f, dot)), rrm[j]);
        float dist = sqrtf(d2);  // exact 0 on diag -> false (matches np)
        if (dist > 4.0f) part |= (1ull << ((rbase + k) * 6 + (mbase + j)));
      }
    }
    part |= __shfl_xor(part, 1);
    part |= __shfl_xor(part, 2);
    mask = part;
  }

  // ---- feature extension, split across the 4 g-lanes (2 output features each) ----
  float myo[6][2];
#pragma unroll
  for (int k = 0; k < 2; ++k) {
    const int o = 2 * g + k;
    const float bo = sbext[o];
#pragma unroll
    for (int n = 0; n < 6; ++n) {
      float s = bo;
#pragma unroll
      for (int f = 0; f < 8; ++f) s = fmaf(bfr[n][f], sWext[o * 8 + f], s);
      myo[n][k] = fmaxf(s, 0.0f);
    }
  }
  const int qbase = (tid & 63) & ~3;  // quad base lane within wave
  float feat[6][8];
#pragma unroll
  for (int n = 0; n < 6; ++n) {
#pragma unroll
    for (int o = 0; o < 8; ++o) {
      feat[n][o] = __shfl(myo[n][o & 1], qbase + (o >> 1), 64);
    }
  }

  // ---- con init: 0.25*bfr so the 4-lane sum contributes the residual exactly once ----
  float con[6][8];
#pragma unroll
  for (int n = 0; n < 6; ++n)
#pragma unroll
    for (int f = 0; f < 8; ++f) con[n][f] = 0.25f * bfr[n][f];

  // ---- this lane's group g ----
  const float* M = sM + g * 65;
  const float* U = sU + g * 9;
  const float* V = sV + g * 9;
  const float* Wg = sWgcn + g * 65;
  const float Cg = sC[g];

  // z[m][f1] = sum_f2 M[f1][f2]*feat[m][f2]
  float z[6][8];
#pragma unroll
  for (int m = 0; m < 6; ++m)
#pragma unroll
    for (int f1 = 0; f1 < 8; ++f1) z[m][f1] = 0.0f;
#pragma unroll
  for (int f1 = 0; f1 < 8; ++f1) {
#pragma unroll
    for (int f2 = 0; f2 < 8; ++f2) {
      const float Mv = M[f1 * 8 + f2];
#pragma unroll
      for (int m = 0; m < 6; ++m) z[m][f1] = fmaf(Mv, feat[m][f2], z[m][f1]);
    }
  }

  float uv[6], vv[6];
#pragma unroll
  for (int n = 0; n < 6; ++n) {
    float su = 0.0f, sv = 0.0f;
#pragma unroll
    for (int f = 0; f < 8; ++f) {
      su = fmaf(U[f], feat[n][f], su);
      sv = fmaf(V[f], feat[n][f], sv);
    }
    uv[n] = su; vv[n] = sv;
  }

  // sim + softmax -> P[6][6]
  float P[6][6];
#pragma unroll
  for (int n = 0; n < 6; ++n) {
    float simr[6];
    float rmax = -INFINITY;
#pragma unroll
    for (int m = 0; m < 6; ++m) {
      float s = 0.0f;
#pragma unroll
      for (int f = 0; f < 8; ++f) s = fmaf(feat[n][f], z[m][f], s);
      s = (s + uv[n] + vv[m] + Cg) * 0.0625f;
      const bool msk = (mask >> (n * 6 + m)) & 1ull;
      simr[m] = msk ? -INFINITY : s;
      rmax = fmaxf(rmax, simr[m]);
    }
    float e6[6], esum = 0.0f;
#pragma unroll
    for (int m = 0; m < 6; ++m) {
      float ev = __expf(simr[m] - rmax);
      e6[m] = ev; esum += ev;
    }
    const float inv = 1.0f / esum;  // diag always unmasked
#pragma unroll
    for (int m = 0; m < 6; ++m) P[n][m] = e6[m] * inv;
  }

  // agg[n][f] = sum_m P[n][m]*feat[m][f]
  float agg[6][8];
#pragma unroll
  for (int n = 0; n < 6; ++n)
#pragma unroll
    for (int f = 0; f < 8; ++f) agg[n][f] = 0.0f;
#pragma unroll
  for (int m = 0; m < 6; ++m)
#pragma unroll
    for (int f = 0; f < 8; ++f) {
      const float fv = feat[m][f];
#pragma unroll
      for (int n = 0; n < 6; ++n) agg[n][f] = fmaf(P[n][m], fv, agg[n][f]);
    }

  // con += relu(0.25*Wgcn_g @ agg)
#pragma unroll
  for (int o = 0; o < 8; ++o) {
    float t6[6] = {0, 0, 0, 0, 0, 0};
#pragma unroll
    for (int f = 0; f < 8; ++f) {
      const float Wv = Wg[o * 8 + f];
#pragma unroll
      for (int n = 0; n < 6; ++n) t6[n] = fmaf(Wv, agg[n][f], t6[n]);
    }
#pragma unroll
    for (int n = 0; n < 6; ++n) con[n][o] += fmaxf(t6[n], 0.0f);
  }

  // ---- butterfly-sum across the 4 g-lanes ----
#pragma unroll
  for (int n = 0; n < 6; ++n)
#pragma unroll
    for (int f = 0; f < 8; ++f) {
      float v = con[n][f];
      v += __shfl_xor(v, 1);
      v += __shfl_xor(v, 2);
      con[n][f] = v;
    }

  // ---- epilogue ----
  float pooled[8];
#pragma unroll
  for (int f = 0; f < 8; ++f) {
    float mx = con[0][f];
#pragma unroll
    for (int n = 1; n < 6; ++n) mx = fmaxf(mx, con[n][f]);
    pooled[f] = mx;
  }
  float scg = sbact[g], sc4 = sbact[4];
#pragma unroll
  for (int f = 0; f < 8; ++f) {
    scg = fmaf(pooled[f], sWact[g * 8 + f], scg);
    sc4 = fmaf(pooled[f], sWact[4 * 8 + f], sc4);
  }
  const size_t ob = (size_t)e * 5;
  out[ob + g] = scg;
  if (g == 0) out[ob + 4] = sc4;
}

extern "C" void kernel_launch(void* const* d_in, const int* in_sizes, int n_in,
                              void* d_out, int out_size, void* d_ws, size_t ws_size,
                              hipStream_t stream) {
  const float* bfeat   = (const float*)d_in[0];
  const float* pos     = (const float*)d_in[1];
  const float* W_ext   = (const float*)d_in[2];
  const float* b_ext   = (const float*)d_in[3];
  const float* W_theta = (const float*)d_in[4];
  const float* b_theta = (const float*)d_in[5];
  const float* W_phi   = (const float*)d_in[6];
  const float* b_phi   = (const float*)d_in[7];
  const float* W_gcn   = (const float*)d_in[8];
  const float* W_act   = (const float*)d_in[9];
  const float* b_act   = (const float*)d_in[10];
  float* out = (float*)d_out;
  float* ws  = (float*)d_ws;

  const int B = in_sizes[0] / 48;  // [B,6,8]

  hipLaunchKernelGGL(gcn_precompute, dim3(81), dim3(256), 0, stream,
                     W_theta, b_theta, W_phi, b_phi, ws);
  const int grid = (B + 63) / 64;
  hipLaunchKernelGGL(gcn_main, dim3(grid), dim3(256), 0, stream,
                     bfeat, pos, W_ext, b_ext, W_gcn, W_act, b_act, ws, out, B);
}

// Round 9
// 87.742 us; speedup vs baseline: 1.0790x; 1.0204x over previous
//
#include <hip/hip_runtime.h>
#include <math.h>

// NG=4, N=6, NFG=8, NFR=256, NACT=5, B=32768
// sim factorization: sim[g,n,m] = (f_n^T M_g f_m + U_g.f_n + V_g.f_m + C_g)/16
// ws layout (floats), R2/R6-proven, UNSCALED:
//   M[g*64+f1*8+f2] @0, U[g*8+f] @256, V[g*8+f] @288, C[g] @320   (324 floats)

// ===== R6's precompute, VERBATIM (proven) =====
__launch_bounds__(256)
__global__ void gcn_precompute(const float* __restrict__ Wt, const float* __restrict__ bt,
                               const float* __restrict__ Wp, const float* __restrict__ bp,
                               float* __restrict__ ws) {
  const int wave = threadIdx.x >> 6, lane = threadIdx.x & 63;
  const int tau = blockIdx.x * 4 + wave;  // 81*4 = 324 exactly
  const float *cA, *cB;
  int sA, sB;
  if (tau < 256) {            // M[g][f1][f2] = sum_r Wt[g,r,f1]*Wp[g,r,f2]
    const int g = tau >> 6, f1 = (tau >> 3) & 7, f2 = tau & 7;
    cA = Wt + g * 2048 + f1; sA = 8;
    cB = Wp + g * 2048 + f2; sB = 8;
  } else if (tau < 288) {     // U[g][f] = sum_r Wt[g,r,f]*bp[g,r]
    const int i = tau - 256, g = i >> 3, f = i & 7;
    cA = Wt + g * 2048 + f;  sA = 8;
    cB = bp + g * 256;       sB = 1;
  } else if (tau < 320) {     // V[g][f] = sum_r Wp[g,r,f]*bt[g,r]
    const int i = tau - 288, g = i >> 3, f = i & 7;
    cA = Wp + g * 2048 + f;  sA = 8;
    cB = bt + g * 256;       sB = 1;
  } else {                    // C[g] = sum_r bt[g,r]*bp[g,r]
    const int g = tau - 320;
    cA = bt + g * 256; sA = 1;
    cB = bp + g * 256; sB = 1;
  }
  float s = 0.0f;
#pragma unroll
  for (int i = 0; i < 4; ++i) {
    const int r = lane + 64 * i;
    s = fmaf(cA[r * sA], cB[r * sB], s);
  }
#pragma unroll
  for (int off = 1; off < 64; off <<= 1) s += __shfl_xor(s, off, 64);
  if (lane == 0) ws[tau] = s;
}

// ---- DPP quad_perm helpers (element's 4 lanes are 4-aligned -> intra-quad) ----
// ctrl = p0 | p1<<2 | p2<<4 | p3<<6
//   xor1 [1,0,3,2] = 0xB1   xor2 [2,3,0,1] = 0x4E
//   bcast0 0x00  bcast1 0x55  bcast2 0xAA  bcast3 0xFF
template <int CTRL>
__device__ __forceinline__ float qperm_f(float v) {
  return __int_as_float(
      __builtin_amdgcn_update_dpp(0, __float_as_int(v), CTRL, 0xF, 0xF, true));
}
template <int CTRL>
__device__ __forceinline__ unsigned qperm_u(unsigned v) {
  return (unsigned)__builtin_amdgcn_update_dpp(0, (int)v, CTRL, 0xF, 0xF, true);
}

// ===== R8's gcn_main; changes: DPP for all cross-lane ops, float4 LDS reads =====
// block=256: 64 elements/block, 4 lanes (one per g) per element. grid = B/64.
__launch_bounds__(256, 2)
__global__ void gcn_main(const float* __restrict__ bfeat, const float* __restrict__ pos,
                         const float* __restrict__ W_ext, const float* __restrict__ b_ext,
                         const float* __restrict__ W_gcn, const float* __restrict__ W_act,
                         const float* __restrict__ b_act, const float* __restrict__ ws,
                         float* __restrict__ out, int B) {
  // strides: M/Wgcn 68 (16B-aligned rows; quad bank bases {0,4,8,12} -> conflict-free),
  //          U/V 12 (bank bases {0,12,24,4}); inter-quad reads are same-addr broadcasts.
  __shared__ __align__(16) float sWext[64];
  __shared__ float sbext[8];
  __shared__ __align__(16) float sM[4 * 68];
  __shared__ __align__(16) float sU[4 * 12];
  __shared__ __align__(16) float sV[4 * 12];
  __shared__ float sC[4];
  __shared__ __align__(16) float sWgcn[4 * 68];  // pre-scaled by 0.25
  __shared__ float sWact[40];
  __shared__ float sbact[5];

  const int tid = threadIdx.x;
  if (tid < 64) sWext[tid] = W_ext[tid];
  if (tid < 8) sbext[tid] = b_ext[tid];
  sM[(tid >> 6) * 68 + (tid & 63)] = ws[tid];
  if (tid < 32) sU[(tid >> 3) * 12 + (tid & 7)] = ws[256 + tid];
  if (tid < 32) sV[(tid >> 3) * 12 + (tid & 7)] = ws[288 + tid];
  if (tid < 4) sC[tid] = ws[320 + tid];
  sWgcn[(tid >> 6) * 68 + (tid & 63)] = 0.25f * W_gcn[tid];
  if (tid < 40) sWact[tid] = W_act[tid];
  if (tid < 5) sbact[tid] = b_act[tid];
  __syncthreads();

  const int e = blockIdx.x * 64 + (tid >> 2);  // batch element
  const int g = tid & 3;                       // relation group
  if (e >= B) return;

  // ---- load positions [6][2] ----
  float px[6], py[6];
  {
    const float4* p4 = (const float4*)(pos + (size_t)e * 12);
    float4 p0 = p4[0], p1 = p4[1], p2 = p4[2];
    px[0] = p0.x; py[0] = p0.y; px[1] = p0.z; py[1] = p0.w;
    px[2] = p1.x; py[2] = p1.y; px[3] = p1.z; py[3] = p1.w;
    px[4] = p2.x; py[4] = p2.y; px[5] = p2.z; py[5] = p2.w;
  }

  // ---- load raw features [6][8] ----
  float bfr[6][8];
  {
    const float4* f4 = (const float4*)(bfeat + (size_t)e * 48);
#pragma unroll
    for (int i = 0; i < 12; ++i) {
      float4 v = f4[i];
      const int n = i >> 1, base = (i & 1) * 4;
      bfr[n][base + 0] = v.x; bfr[n][base + 1] = v.y;
      bfr[n][base + 2] = v.z; bfr[n][base + 3] = v.w;
    }
  }

  // ---- position mask, 4-way split across the quad (R8, DPP combine) ----
  float rr[6];
#pragma unroll
  for (int n = 0; n < 6; ++n)
    rr[n] = __fadd_rn(__fmul_rn(px[n], px[n]), __fmul_rn(py[n], py[n]));
  unsigned long long mask;
  {
    const int h2 = (g >> 1) & 1, q2 = g & 1;
    float pxn[3], pyn[3], rrn[3], pxm[3], pym[3], rrm[3];
#pragma unroll
    for (int k = 0; k < 3; ++k) {
      pxn[k] = h2 ? px[k + 3] : px[k];
      pyn[k] = h2 ? py[k + 3] : py[k];
      rrn[k] = h2 ? rr[k + 3] : rr[k];
      pxm[k] = q2 ? px[k + 3] : px[k];
      pym[k] = q2 ? py[k + 3] : py[k];
      rrm[k] = q2 ? rr[k + 3] : rr[k];
    }
    unsigned long long part = 0ull;
    const int rbase = 3 * h2, mbase = 3 * q2;
#pragma unroll
    for (int k = 0; k < 3; ++k) {
#pragma unroll
      for (int j = 0; j < 3; ++j) {
        float dot = __fadd_rn(__fmul_rn(pxn[k], pxm[j]), __fmul_rn(pyn[k], pym[j]));
        float d2 = __fadd_rn(__fsub_rn(rrn[k], __fmul_rn(2.0f, dot)), rrm[j]);
        float dist = sqrtf(d2);  // exact numpy fp32 sequence; diag NaN -> false
        if (dist > 4.0f) part |= (1ull << ((rbase + k) * 6 + (mbase + j)));
      }
    }
    unsigned lo = (unsigned)part, hi = (unsigned)(part >> 32);
    lo |= qperm_u<0xB1>(lo); hi |= qperm_u<0xB1>(hi);
    lo |= qperm_u<0x4E>(lo); hi |= qperm_u<0x4E>(hi);
    mask = (unsigned long long)lo | ((unsigned long long)hi << 32);
  }

  // ---- feature extension, split across the 4 g-lanes (2 output features each) ----
  float myo[6][2];
#pragma unroll
  for (int k = 0; k < 2; ++k) {
    const int o = 2 * g + k;
    const float4 w0 = *(const float4*)(sWext + o * 8);
    const float4 w1 = *(const float4*)(sWext + o * 8 + 4);
    const float bo = sbext[o];
#pragma unroll
    for (int n = 0; n < 6; ++n) {
      float s = bo;
      s = fmaf(bfr[n][0], w0.x, s); s = fmaf(bfr[n][1], w0.y, s);
      s = fmaf(bfr[n][2], w0.z, s); s = fmaf(bfr[n][3], w0.w, s);
      s = fmaf(bfr[n][4], w1.x, s); s = fmaf(bfr[n][5], w1.y, s);
      s = fmaf(bfr[n][6], w1.z, s); s = fmaf(bfr[n][7], w1.w, s);
      myo[n][k] = fmaxf(s, 0.0f);
    }
  }
  // all-gather feat[6][8] via DPP quad broadcasts (lane j holds o=2j,2j+1)
  float feat[6][8];
#pragma unroll
  for (int n = 0; n < 6; ++n) {
    feat[n][0] = qperm_f<0x00>(myo[n][0]);
    feat[n][1] = qperm_f<0x00>(myo[n][1]);
    feat[n][2] = qperm_f<0x55>(myo[n][0]);
    feat[n][3] = qperm_f<0x55>(myo[n][1]);
    feat[n][4] = qperm_f<0xAA>(myo[n][0]);
    feat[n][5] = qperm_f<0xAA>(myo[n][1]);
    feat[n][6] = qperm_f<0xFF>(myo[n][0]);
    feat[n][7] = qperm_f<0xFF>(myo[n][1]);
  }

  // ---- con init: 0.25*bfr so the 4-lane sum contributes the residual exactly once ----
  float con[6][8];
#pragma unroll
  for (int n = 0; n < 6; ++n)
#pragma unroll
    for (int f = 0; f < 8; ++f) con[n][f] = 0.25f * bfr[n][f];

  // ---- this lane's group tables (float4 LDS reads) ----
  const float4* M4 = (const float4*)(sM + g * 68);
  const float4* W4 = (const float4*)(sWgcn + g * 68);
  const float4* U4 = (const float4*)(sU + g * 12);
  const float4* V4 = (const float4*)(sV + g * 12);
  const float Cg = sC[g];

  // z[m][f1] = sum_f2 M[f1][f2]*feat[m][f2]  (f2 ascending -> same fp order as R8)
  float z[6][8];
#pragma unroll
  for (int f1 = 0; f1 < 8; ++f1) {
    const float4 a = M4[2 * f1], b = M4[2 * f1 + 1];
#pragma unroll
    for (int m = 0; m < 6; ++m) {
      float s = 0.0f;
      s = fmaf(a.x, feat[m][0], s); s = fmaf(a.y, feat[m][1], s);
      s = fmaf(a.z, feat[m][2], s); s = fmaf(a.w, feat[m][3], s);
      s = fmaf(b.x, feat[m][4], s); s = fmaf(b.y, feat[m][5], s);
      s = fmaf(b.z, feat[m][6], s); s = fmaf(b.w, feat[m][7], s);
      z[m][f1] = s;
    }
  }

  float uv[6], vv[6];
  {
    const float4 u0 = U4[0], u1 = U4[1];
    const float4 v0 = V4[0], v1 = V4[1];
#pragma unroll
    for (int n = 0; n < 6; ++n) {
      float su = 0.0f, sv = 0.0f;
      su = fmaf(u0.x, feat[n][0], su); su = fmaf(u0.y, feat[n][1], su);
      su = fmaf(u0.z, feat[n][2], su); su = fmaf(u0.w, feat[n][3], su);
      su = fmaf(u1.x, feat[n][4], su); su = fmaf(u1.y, feat[n][5], su);
      su = fmaf(u1.z, feat[n][6], su); su = fmaf(u1.w, feat[n][7], su);
      sv = fmaf(v0.x, feat[n][0], sv); sv = fmaf(v0.y, feat[n][1], sv);
      sv = fmaf(v0.z, feat[n][2], sv); sv = fmaf(v0.w, feat[n][3], sv);
      sv = fmaf(v1.x, feat[n][4], sv); sv = fmaf(v1.y, feat[n][5], sv);
      sv = fmaf(v1.z, feat[n][6], sv); sv = fmaf(v1.w, feat[n][7], sv);
      uv[n] = su; vv[n] = sv;
    }
  }

  // sim + softmax -> P[6][6]
  float P[6][6];
#pragma unroll
  for (int n = 0; n < 6; ++n) {
    float simr[6];
    float rmax = -INFINITY;
#pragma unroll
    for (int m = 0; m < 6; ++m) {
      float s = 0.0f;
#pragma unroll
      for (int f = 0; f < 8; ++f) s = fmaf(feat[n][f], z[m][f], s);
      s = (s + uv[n] + vv[m] + Cg) * 0.0625f;
      const bool msk = (mask >> (n * 6 + m)) & 1ull;
      simr[m] = msk ? -INFINITY : s;
      rmax = fmaxf(rmax, simr[m]);
    }
    float e6[6], esum = 0.0f;
#pragma unroll
    for (int m = 0; m < 6; ++m) {
      float ev = __expf(simr[m] - rmax);
      e6[m] = ev; esum += ev;
    }
    const float inv = 1.0f / esum;  // diag always unmasked
#pragma unroll
    for (int m = 0; m < 6; ++m) P[n][m] = e6[m] * inv;
  }

  // agg[n][f] = sum_m P[n][m]*feat[m][f]
  float agg[6][8];
#pragma unroll
  for (int n = 0; n < 6; ++n)
#pragma unroll
    for (int f = 0; f < 8; ++f) agg[n][f] = 0.0f;
#pragma unroll
  for (int m = 0; m < 6; ++m)
#pragma unroll
    for (int f = 0; f < 8; ++f) {
      const float fv = feat[m][f];
#pragma unroll
      for (int n = 0; n < 6; ++n) agg[n][f] = fmaf(P[n][m], fv, agg[n][f]);
    }

  // con += relu(0.25*Wgcn_g @ agg)   (f ascending -> same fp order as R8)
#pragma unroll
  for (int o = 0; o < 8; ++o) {
    const float4 a = W4[2 * o], b = W4[2 * o + 1];
#pragma unroll
    for (int n = 0; n < 6; ++n) {
      float s = 0.0f;
      s = fmaf(a.x, agg[n][0], s); s = fmaf(a.y, agg[n][1], s);
      s = fmaf(a.z, agg[n][2], s); s = fmaf(a.w, agg[n][3], s);
      s = fmaf(b.x, agg[n][4], s); s = fmaf(b.y, agg[n][5], s);
      s = fmaf(b.z, agg[n][6], s); s = fmaf(b.w, agg[n][7], s);
      con[n][o] += fmaxf(s, 0.0f);
    }
  }

  // ---- butterfly-sum across the 4 g-lanes via DPP (xor1, xor2) ----
#pragma unroll
  for (int n = 0; n < 6; ++n)
#pragma unroll
    for (int f = 0; f < 8; ++f) {
      float v = con[n][f];
      v += qperm_f<0xB1>(v);
      v += qperm_f<0x4E>(v);
      con[n][f] = v;
    }

  // ---- epilogue ----
  float pooled[8];
#pragma unroll
  for (int f = 0; f < 8; ++f) {
    float mx = con[0][f];
#pragma unroll
    for (int n = 1; n < 6; ++n) mx = fmaxf(mx, con[n][f]);
    pooled[f] = mx;
  }
  float scg = sbact[g], sc4 = sbact[4];
#pragma unroll
  for (int f = 0; f < 8; ++f) {
    scg = fmaf(pooled[f], sWact[g * 8 + f], scg);
    sc4 = fmaf(pooled[f], sWact[4 * 8 + f], sc4);
  }
  const size_t ob = (size_t)e * 5;
  out[ob + g] = scg;
  if (g == 0) out[ob + 4] = sc4;
}

extern "C" void kernel_launch(void* const* d_in, const int* in_sizes, int n_in,
                              void* d_out, int out_size, void* d_ws, size_t ws_size,
                              hipStream_t stream) {
  const float* bfeat   = (const float*)d_in[0];
  const float* pos     = (const float*)d_in[1];
  const float* W_ext   = (const float*)d_in[2];
  const float* b_ext   = (const float*)d_in[3];
  const float* W_theta = (const float*)d_in[4];
  const float* b_theta = (const float*)d_in[5];
  const float* W_phi   = (const float*)d_in[6];
  const float* b_phi   = (const float*)d_in[7];
  const float* W_gcn   = (const float*)d_in[8];
  const float* W_act   = (const float*)d_in[9];
  const float* b_act   = (const float*)d_in[10];
  float* out = (float*)d_out;
  float* ws  = (float*)d_ws;

  const int B = in_sizes[0] / 48;  // [B,6,8]

  hipLaunchKernelGGL(gcn_precompute, dim3(81), dim3(256), 0, stream,
                     W_theta, b_theta, W_phi, b_phi, ws);
  const int grid = (B + 63) / 64;
  hipLaunchKernelGGL(gcn_main, dim3(grid), dim3(256), 0, stream,
                     bfeat, pos, W_ext, b_ext, W_gcn, W_act, b_act, ws, out, B);
}